// Round 7
// baseline (625.269 us; speedup 1.0000x reference)
//
#include <hip/hip_runtime.h>
#include <hip/hip_bf16.h>
#include <cstdint>

#define SDIM 200
#define HDIM 128
#define IDIM 4
#define BDIM 1024
#define LDK 72            // bf16 leading dim per 64-wide K-half (144 B rows)
#define REG_US 9216       // 128*LDK ushorts per subregion (hi or lo, one K-half)
#define HALF_US 18432     // ushorts per K-half image (hi+lo) = 36,864 B
#define IMG_US 36864      // ushorts per (s,ii) full image = 73,728 B

typedef __attribute__((ext_vector_type(8))) short short8;
typedef __attribute__((ext_vector_type(4))) float f32x4;

__device__ __forceinline__ ushort f32_to_bf16u(float f) {
    uint32_t u = __builtin_bit_cast(uint32_t, f);
    u += 0x7FFFu + ((u >> 16) & 1u);   // RNE
    return (ushort)(u >> 16);
}
__device__ __forceinline__ float bf16u_to_f32(ushort h) {
    uint32_t u = ((uint32_t)h) << 16;
    return __builtin_bit_cast(float, u);
}
__device__ __forceinline__ void split8(const float* p, uint4* hi, uint4* lo) {
    union { ushort u[8]; uint4 v; } xh, xl;
    #pragma unroll
    for (int j = 0; j < 8; ++j) {
        float f = p[j];
        ushort h = f32_to_bf16u(f);
        float r = f - bf16u_to_f32(h);
        xh.u[j] = h;
        xl.u[j] = f32_to_bf16u(r);
    }
    *hi = xh.v; *lo = xl.v;
}

// async global->LDS, 16 B per lane; LDS dest = wave-uniform base + lane*16
__device__ __forceinline__ void gload16(const void* g, void* l) {
    __builtin_amdgcn_global_load_lds(
        (const __attribute__((address_space(1))) void*)g,
        (__attribute__((address_space(3))) void*)l,
        16, 0, 0);
}

// ---------------------------------------------------------------------------
// Kernel 0 (R9, unchanged): W prepass -> exact LDS images. Per (s,ii):
//   [Wh0 | Wl0 | Wh1 | Wl1], each 128 rows x LDK(72) ushorts, pad zeroed.
// ---------------------------------------------------------------------------
__global__ __launch_bounds__(256) void wstage(const float* __restrict__ w,
                                              ushort* __restrict__ img) {
    const int blk = blockIdx.x;            // 800 = (s<<2) | ii
    const int s = blk >> 2, ii = blk & 3;
    const int t = threadIdx.x;
    const float* wB = w + ((size_t)s * (IDIM * HDIM) + (size_t)ii * HDIM) * HDIM;
    ushort* dst = img + (size_t)blk * IMG_US;

    for (int g = t; g < 2048; g += 256) {  // 8-elem groups, row-major linear
        uint4 hi, lo;
        split8(wB + (size_t)g * 8, &hi, &lo);
        int c0 = g >> 4;                   // output col (B-row) 0..127
        int st = (g >> 3) & 1;             // K-half
        int kl = (g & 7) * 8;              // k offset within half, 0..56
        *(uint4*)(dst + st * HALF_US +          c0 * LDK + kl) = hi;
        *(uint4*)(dst + st * HALF_US + REG_US + c0 * LDK + kl) = lo;
    }
    const uint4 z = {0u, 0u, 0u, 0u};      // zero pads [64..72) per row, 16 B
    for (int p = t; p < 512; p += 256) {
        int rg = p >> 7, c0 = p & 127;
        *(uint4*)(dst + rg * REG_US + c0 * LDK + 64) = z;
    }
}

// ---------------------------------------------------------------------------
// Kernel 1 (R10): M=32 tile, occupancy-first. 256 thr = 4 waves, wave wn owns
// 32-col quarter of each 128-col ii-slab. Per lane: A = 2 rows x full K x
// hi/lo = 64 VGPR; acc 16; B-frags 16 -> ~110 total; __launch_bounds__(256,4)
// forces <=128 -> with LDS 36,864 B single-buffer: 4 blocks/CU = 16 waves/CU
// (2x every prior config; all prior rounds sat at 8 due to VGPR 64-granule
// rounding). Grid = SDIM x nbt, s-major: co-resident blocks share the same
// s-image -> stage DMA is L2-hit (per-XCD img set ~2.4 MB < 4 MB L2).
// ---------------------------------------------------------------------------
__global__ __launch_bounds__(256, 4) void hat_gemm(const float* __restrict__ item,
                                                   const ushort* __restrict__ img,
                                                   float* __restrict__ hat,
                                                   int b0, int nbt) {
    __shared__ ushort lds[HALF_US];        // 36,864 B: one K-half image (hi|lo)

    const int blk = blockIdx.x;
    const int s  = blk / nbt;              // s-major: neighbors share s
    const int bt = blk % nbt;              // 32-row batch tile
    const int t  = threadIdx.x;
    const int wn = t >> 6, lane = t & 63;  // wn in [0,4): 32-col quarter
    const int m0 = lane & 15, q = lane >> 4;

    // ---- A: 32 rows; lane holds rows tm*16+m0 (tm<2), full K, hi/lo ----
    short8 ah[2][2][2], al[2][2][2];       // [st][kk][tm] = 16 short8 = 64 VGPR
    {
        const float* ib = item +
            ((size_t)(b0 + bt * 32 + m0) * SDIM + s) * HDIM;
        #pragma unroll
        for (int tm = 0; tm < 2; ++tm) {
            const float* p = ib + (size_t)(tm * 16) * (SDIM * HDIM);
            #pragma unroll
            for (int st = 0; st < 2; ++st)
                #pragma unroll
                for (int kk = 0; kk < 2; ++kk) {
                    uint4 hi, lo;
                    split8(p + st * 64 + kk * 32 + q * 8, &hi, &lo);
                    ah[st][kk][tm] = __builtin_bit_cast(short8, hi);
                    al[st][kk][tm] = __builtin_bit_cast(short8, lo);
                }
        }
    }

    const ushort* imgS = img + (size_t)(s * IDIM) * IMG_US;

    #pragma unroll 1
    for (int ii = 0; ii < IDIM; ++ii) {
        f32x4 acc[2][2];
        #pragma unroll
        for (int tm = 0; tm < 2; ++tm)
            #pragma unroll
            for (int tn = 0; tn < 2; ++tn)
                acc[tm][tn] = (f32x4){0.f, 0.f, 0.f, 0.f};

        #pragma unroll
        for (int st = 0; st < 2; ++st) {
            __syncthreads();               // prior stage's LDS reads done

            // ---- stage one K-half image: 2304 x 16 B DMA (L2-hot, s-major)
            {
                const char* src = (const char*)(imgS + (size_t)ii * IMG_US
                                                + (size_t)st * HALF_US);
                char* dst = (char*)lds;
                #pragma unroll
                for (int i = 0; i < 9; ++i) {
                    const int off = (i * 256 + wn * 64) * 16;
                    gload16(src + off + lane * 16, dst + off);
                }
            }
            __syncthreads();               // DMA landed (vmcnt drained)

            const ushort* Wh = lds;
            const ushort* Wl = lds + REG_US;
            #pragma unroll
            for (int kk = 0; kk < 2; ++kk) {
                const int kof = kk * 32 + q * 8;
                short8 bh[2], bl2[2];
                #pragma unroll
                for (int tn = 0; tn < 2; ++tn) {
                    int ro = (wn * 32 + tn * 16 + m0) * LDK + kof;
                    bh[tn]  = *(const short8*)(&Wh[ro]);
                    bl2[tn] = *(const short8*)(&Wl[ro]);
                }
                #pragma unroll
                for (int tm = 0; tm < 2; ++tm)
                    #pragma unroll
                    for (int tn = 0; tn < 2; ++tn) {
                        acc[tm][tn] = __builtin_amdgcn_mfma_f32_16x16x32_bf16(
                            ah[st][kk][tm], bl2[tn], acc[tm][tn], 0, 0, 0);
                        acc[tm][tn] = __builtin_amdgcn_mfma_f32_16x16x32_bf16(
                            al[st][kk][tm], bh[tn], acc[tm][tn], 0, 0, 0);
                        acc[tm][tn] = __builtin_amdgcn_mfma_f32_16x16x32_bf16(
                            ah[st][kk][tm], bh[tn], acc[tm][tn], 0, 0, 0);
                    }
            }
        }

        // ---- direct acc -> hat stores (16 lanes x 16 cols = 64-B segments)
        #pragma unroll
        for (int tm = 0; tm < 2; ++tm) {
            #pragma unroll
            for (int tn = 0; tn < 2; ++tn) {
                const int col = wn * 32 + tn * 16 + m0;
                #pragma unroll
                for (int rg = 0; rg < 4; ++rg) {
                    const size_t bl_ = (size_t)(bt * 32 + tm * 16 + q * 4 + rg);
                    hat[((bl_ * IDIM + ii) * SDIM + s) * HDIM + col] =
                        acc[tm][tn][rg];
                }
            }
        }
    }
}

// ---------------------------------------------------------------------------
// Kernel 2 (R8/R9, unchanged): routing, 512 thr, 8 barriers, redundant phases.
// ---------------------------------------------------------------------------
__global__ __launch_bounds__(512) void routing4(const float* __restrict__ hat,
                                                const int* __restrict__ mask,
                                                float* __restrict__ out, int b0) {
    __shared__ float cw[SDIM];
    __shared__ float icp[16 * HDIM];
    __shared__ float icf[HDIM];
    __shared__ int   mk[SDIM];

    const int blk = blockIdx.x;
    const int bl = blk >> 2, ii = blk & 3;
    const int b = b0 + bl;
    const int t = threadIdx.x, lane = t & 63, wv = t >> 6;
    const int hq = (t & 31) * 4;
    const int sg = t >> 5;                 // [0,16)
    const bool has13 = (sg < 8);
    const float* base = hat + ((size_t)bl * IDIM + ii) * (SDIM * HDIM);

    if (t < SDIM) mk[t] = mask[(size_t)b * SDIM + t];

    float4 pf[13];
    #pragma unroll
    for (int j = 0; j < 12; ++j)
        pf[j] = *(const float4*)(base + (size_t)(sg + 16 * j) * HDIM + hq);
    pf[12] = has13 ? *(const float4*)(base + (size_t)(sg + 192) * HDIM + hq)
                   : (float4){0.f, 0.f, 0.f, 0.f};
    __syncthreads();                       // mk ready                     [B1]

    {
        float4 u = {0.f, 0.f, 0.f, 0.f};
        #pragma unroll
        for (int j = 0; j < 12; ++j) {
            if (mk[sg + 16 * j]) {
                u.x += pf[j].x; u.y += pf[j].y; u.z += pf[j].z; u.w += pf[j].w;
            }
        }
        if (has13 && mk[sg + 192]) {
            u.x += pf[12].x; u.y += pf[12].y; u.z += pf[12].z; u.w += pf[12].w;
        }
        *(float4*)(&icp[sg * HDIM + hq]) = u;
    }
    __syncthreads();                       // icp ready                    [B2]
    {
        float i0 = 0.f, i1 = 0.f;
        #pragma unroll
        for (int g = 0; g < 16; ++g) {
            i0 += icp[g * HDIM + lane];
            i1 += icp[g * HDIM + lane + 64];
        }
        i0 *= (1.0f / 200.0f);
        i1 *= (1.0f / 200.0f);
        float p = i0 * i0 + i1 * i1;
        #pragma unroll
        for (int off = 32; off > 0; off >>= 1) p += __shfl_xor(p, off);
        float fac = p / (1.0f + p) / sqrtf(p + 1e-9f);
        if (wv == 0) {
            icf[lane] = i0 * fac;
            icf[lane + 64] = i1 * fac;
        }
    }
    __syncthreads();                       // icf ready                    [B3]

    for (int iter = 1; iter <= 2; ++iter) {
        float4 c4 = *(const float4*)(&icf[hq]);
        #pragma unroll
        for (int j = 0; j < 13; ++j) {
            float d = fmaf(pf[j].x, c4.x, fmaf(pf[j].y, c4.y,
                      fmaf(pf[j].z, c4.z, pf[j].w * c4.w)));
            d += __shfl_xor(d, 16);
            d += __shfl_xor(d, 8);
            d += __shfl_xor(d, 4);
            d += __shfl_xor(d, 2);
            d += __shfl_xor(d, 1);
            if ((t & 31) == 0 && (j < 12 || has13)) {
                int s = sg + 16 * j;
                cw[s] = (iter == 1) ? d : cw[s] + d;
            }
        }
        __syncthreads();                   // cw ready                 [B4/B6]

        float m = fmaxf(cw[lane], fmaxf(cw[lane + 64], cw[lane + 128]));
        if (lane < SDIM - 192) m = fmaxf(m, cw[lane + 192]);
        #pragma unroll
        for (int off = 32; off > 0; off >>= 1) m = fmaxf(m, __shfl_xor(m, off));

        float D = __expf(cw[lane] - m) + __expf(cw[lane + 64] - m)
                + __expf(cw[lane + 128] - m)
                + ((lane < SDIM - 192) ? __expf(cw[lane + 192] - m) : 0.0f);
        #pragma unroll
        for (int off = 32; off > 0; off >>= 1) D += __shfl_xor(D, off);

        {
            float4 u = {0.f, 0.f, 0.f, 0.f};
            #pragma unroll
            for (int j = 0; j < 12; ++j) {
                int s = sg + 16 * j;
                float wgt = mk[s] ? __expf(cw[s] - m) : 0.0f;
                u.x = fmaf(wgt, pf[j].x, u.x);
                u.y = fmaf(wgt, pf[j].y, u.y);
                u.z = fmaf(wgt, pf[j].z, u.z);
                u.w = fmaf(wgt, pf[j].w, u.w);
            }
            float wgt = (has13 && mk[sg + 192]) ? __expf(cw[sg + 192] - m) : 0.0f;
            u.x = fmaf(wgt, pf[12].x, u.x);
            u.y = fmaf(wgt, pf[12].y, u.y);
            u.z = fmaf(wgt, pf[12].z, u.z);
            u.w = fmaf(wgt, pf[12].w, u.w);
            *(float4*)(&icp[sg * HDIM + hq]) = u;
        }
        __syncthreads();                   // icp ready                [B5/B7]

        {
            float i0 = 0.f, i1 = 0.f;
            #pragma unroll
            for (int g = 0; g < 16; ++g) {
                i0 += icp[g * HDIM + lane];
                i1 += icp[g * HDIM + lane + 64];
            }
            i0 /= D;
            i1 /= D;
            float p = i0 * i0 + i1 * i1;
            #pragma unroll
            for (int off = 32; off > 0; off >>= 1) p += __shfl_xor(p, off);
            float fac = p / (1.0f + p) / sqrtf(p + 1e-9f);
            if (iter == 1) {
                if (wv == 0) {
                    icf[lane] = i0 * fac;
                    icf[lane + 64] = i1 * fac;
                }
            } else {
                if (wv == 0) {
                    out[((size_t)b * IDIM + ii) * HDIM + lane]      = i0 * fac;
                    out[((size_t)b * IDIM + ii) * HDIM + lane + 64] = i1 * fac;
                }
            }
        }
        if (iter == 1) __syncthreads();    // icf ready                   [B8]
    }
}

extern "C" void kernel_launch(void* const* d_in, const int* in_sizes, int n_in,
                              void* d_out, int out_size, void* d_ws, size_t ws_size,
                              hipStream_t stream) {
    const float* item = nullptr;
    const int*   msk  = nullptr;
    const float* w    = nullptr;
    for (int i = 0; i < n_in; ++i) {
        if (in_sizes[i] == BDIM * SDIM * HDIM)             item = (const float*)d_in[i];
        else if (in_sizes[i] == BDIM * SDIM)               msk  = (const int*)d_in[i];
        else if (in_sizes[i] == SDIM * IDIM * HDIM * HDIM) w    = (const float*)d_in[i];
    }
    if (!item) item = (const float*)d_in[0];
    if (!msk)  msk  = (const int*)d_in[1];
    if (!w)    w    = (const float*)d_in[2];

    // ws layout: [w images 58.98 MB][hat chunk 209.7 MB]
    const size_t imgBytes = (size_t)SDIM * IDIM * IMG_US * sizeof(ushort);
    ushort* wimg = (ushort*)d_ws;
    float*  hat  = (float*)((char*)d_ws + imgBytes);
    float*  out  = (float*)d_out;

    wstage<<<SDIM * IDIM, 256, 0, stream>>>(w, wimg);

    const size_t perB = (size_t)IDIM * SDIM * HDIM * sizeof(float);
    size_t hatCap = (ws_size - imgBytes) / perB;
    int chunk = 512;
    if (hatCap < (size_t)chunk) chunk = (int)((hatCap / 128) * 128);
    if (chunk < 128) chunk = 128;
    for (int bb = 0; bb < BDIM; bb += chunk) {
        int cb = (BDIM - bb < chunk) ? (BDIM - bb) : chunk;
        int nbt = cb / 32;                 // M=32 tiles
        hat_gemm<<<SDIM * nbt, 256, 0, stream>>>(item, wimg, hat, bb, nbt);
        routing4<<<cb * IDIM, 512, 0, stream>>>(hat, msk, out, bb);
    }
}